// Round 12
// baseline (46.848 us; speedup 1.0000x reference)
//
#include <hip/hip_runtime.h>

// ---------------------------------------------------------------------------
// Depthwise 1-D full correlation, per (batch, filter):
//   out[t] = sum_s y[s] * w[2047 + s - t],   t, s in [0, 4096)
// Slab per (b,f) (ushort units): [y 4096 | w 4096 | out f32 4096] = 16384
// K0: transpose/convert X[b][s][c] (f32) -> bf16 slabs (y, w)
// K1: 2048 blocks = (b, f, half); half-t output range each. 16x16x32 MFMA,
//     fp32 acc; 8h x 2p per wave (B-window 8, acc 8 -> ~4 waves/SIMD);
//     WB (+1-shifted w) built during staging from registers; 2-deep static
//     A prefetch; swizzled f32x4 pairwise reduction; out -> disjoint slab
//     third (block-private).
// K2: 32x32 transpose out-regions -> out[b][t][f]; f32x4 both sides; one
//     writer per 128-B output line.
// All kernels decode b = bid&31 so bid%8 == b%8: slab pipeline XCD-local.
// ---------------------------------------------------------------------------

#define T_LEN 4096
#define F_CH  32
#define SLAB_US 16384             // y[4096] | w[4096] | out f32[4096]
#define O_OFF   8192

// K1 LDS layout (ushort units)
#define Y_SZ   6400               // 800 granules: e_local in [0,6400)
#define WAo    6400               // WA[16+i] = w[i]
#define WBo    10544              // WB[15+i] = w[i]  (built during staging)
#define LDS_US 14912              // 29824 B (tail pad covers A prefetch reads)

using short8 = __attribute__((ext_vector_type(8))) short;
using f32x4  = __attribute__((ext_vector_type(4))) float;
using uint4v = __attribute__((ext_vector_type(4))) unsigned int;

__device__ __forceinline__ unsigned short bf16b(float x) {
    unsigned int u = __float_as_uint(x);
    u += 0x7FFFu + ((u >> 16) & 1u);      // RNE
    return (unsigned short)(u >> 16);
}

// y swizzle: granule g -> g ^ ((g>>3)&7)  (bijective per 8-set)
#define GSWZ(g)  ((g) ^ (((g) >> 3) & 7))
#define YADDR(e) ((GSWZ((e) >> 3)) << 3)
// reduction swizzle within a 256-dword h-block (R5-verified)
#define RSWZ(j)  ((j) ^ ((((j) >> 4) & 7) << 2))

// ---------------------------------------------------------------------------
__global__ __launch_bounds__(256)
void k0_stage(const float* __restrict__ X, unsigned short* __restrict__ ws) {
    __shared__ unsigned short tile[64 * 130];
    const int tid = threadIdx.x;
    const int b  = blockIdx.x & 31;              // bid%8 == b%8 (XCD-local)
    const int s0 = (blockIdx.x >> 5) << 7;       // 128-row tile

    const float* xb = X + ((size_t)b * T_LEN + s0) * 64;
#pragma unroll
    for (int i = 0; i < 8; ++i) {
        int d4 = 4 * (tid + 256 * i);            // dword idx, 4 per thread
        int row = d4 >> 6, c0 = d4 & 63;
        f32x4 xv = *(const f32x4*)(xb + (size_t)row * 64 + c0);
#pragma unroll
        for (int k = 0; k < 4; ++k)
            tile[(c0 + k) * 130 + row] = bf16b(xv[k]);
    }
    __syncthreads();

    // y & w slabs, dword stores (coalesced per wave)
#pragma unroll
    for (int i = 0; i < 16; ++i) {
        int dw = tid + 256 * i;                  // 0..4095
        int c = dw >> 6, j0 = (dw & 63) * 2;
        unsigned int two = (unsigned int)tile[c * 130 + j0]
                         | ((unsigned int)tile[c * 130 + j0 + 1] << 16);
        unsigned short* slab;
        int off;
        if (c < 32) { slab = ws + (size_t)(b * 32 + c) * SLAB_US; off = s0 + j0; }
        else { slab = ws + (size_t)(b * 32 + (c - 32)) * SLAB_US; off = 4096 + s0 + j0; }
        *(unsigned int*)(slab + off) = two;
    }
}

// ---------------------------------------------------------------------------
__global__ __launch_bounds__(256, 4)
void corr1d_mfma_kernel(unsigned short* __restrict__ ws) {
    __shared__ __align__(16) unsigned short lds[LDS_US];
    const int tid = threadIdx.x;
    const int bid = blockIdx.x;
    const int b    = bid & 31;                   // bid%8 == b%8 (XCD-local)
    const int f    = (bid >> 5) & 31;
    const int half = bid >> 10;                  // 0 or 1
    unsigned short* slab = ws + (size_t)(b * 32 + f) * SLAB_US;

    // ---- zero W pad regions ----
    f32x4 z4 = (f32x4)0.0f;
    if (tid < 2)       *(f32x4*)(lds + WAo + 8 * tid) = z4;              // WA [0,16)
    else if (tid < 6)  *(f32x4*)(lds + WAo + 4112 + 8 * (tid - 2)) = z4; // WA [4112,4144)
    else if (tid == 6) {
        *(f32x4*)(lds + WBo) = z4;                                       // WB [0,8)
        for (int i = 8; i < 14; ++i) lds[WBo + i] = 0;                   // WB [8,14)
    } else if (tid >= 8 && tid < 12)
        *(f32x4*)(lds + WBo + 4112 + 8 * (tid - 8)) = z4;                // WB [4112,4144)

    // ---- stage y window (800 granules, swizzled; pads from zero regs) ----
    //   e_local = e_global - 2048*half; data granule c = g - 256*(1-half)
    const uint4v* sv = (const uint4v*)slab;      // y granules [0,512)
    const int cofs = 256 * (1 - half);
    const uint4v zz = {0u, 0u, 0u, 0u};
#pragma unroll
    for (int r = 0; r < 3; ++r) {
        int g = tid + 256 * r;                   // 0..767
        int c = g - cofs;
        uint4v vy = (c >= 0 && c < 512) ? sv[c] : zz;
        *(uint4v*)(lds + (GSWZ(g) << 3)) = vy;
    }
    if (tid < 32) {
        int g = 768 + tid;                       // 768..799
        int c = g - cofs;
        uint4v vy = (c >= 0 && c < 512) ? sv[c] : zz;
        *(uint4v*)(lds + (GSWZ(g) << 3)) = vy;
    }

    // ---- stage WA, build WB (+1 shift) from registers ----
    unsigned int* wb32 = (unsigned int*)(lds + WBo);
#pragma unroll
    for (int r = 0; r < 2; ++r) {
        int c = tid + 256 * r;                   // 0..511
        uint4v vw = sv[512 + c];                 // w[8c .. 8c+7]
        *(uint4v*)(lds + WAo + 16 + 8 * c) = vw;
        unsigned int wm1 = (c == 0) ? 0u
                         : (unsigned int)slab[4096 + 8 * c - 1];
        unsigned int v0 = vw[0], v1 = vw[1], v2 = vw[2], v3 = vw[3];
        wb32[7 + 4 * c + 0] = (wm1 & 0xFFFFu) | (v0 << 16);
        wb32[7 + 4 * c + 1] = (v0 >> 16) | (v1 << 16);
        wb32[7 + 4 * c + 2] = (v1 >> 16) | (v2 << 16);
        wb32[7 + 4 * c + 3] = (v2 >> 16) | (v3 << 16);
        if (c == 511) wb32[2055] = (v3 >> 16);   // (w[4095], 0)
    }
    __syncthreads();

    // ---- compute: 8 h x 2 passes per wave (B-window 8, all static) ----
    const int lane = tid & 63;
    const int wv   = tid >> 6;
    const int nn   = lane & 15;
    const int q    = lane >> 4;
    const int ko   = q << 3;

    f32x4 acc[8];
#pragma unroll
    for (int h = 0; h < 8; ++h) acc[h] = (f32x4)0.0f;

    short8 cache[8];

    const int tiOdd = nn & 1;
    const unsigned short* wbase = tiOdd ? &lds[WAo] : &lds[WBo];
    const int aoff0 = (tiOdd ? 15 : 14) + ko - nn;           // even, >= 0
    const unsigned short* ybase = &lds[0];
    const int yoff0 = 16 * nn + ko;

    for (int pp = 0; pp < 2; ++pp) {
        const int p = wv * 2 + pp;                           // pass 0..7
        const int yoff = yoff0 + 32 * p;
        const unsigned int* abase =
            (const unsigned int*)(wbase + (aoff0 + 32 * p));

#pragma unroll
        for (int s = 0; s < 8; ++s)
            cache[s] = *(const short8*)(ybase + YADDR(yoff + 256 * s));

        uint4v aPre[2];
#pragma unroll
        for (int s = 0; s < 2; ++s) {
            const unsigned int* ap = abase + 128 * s;
            aPre[s][0] = ap[0]; aPre[s][1] = ap[1];
            aPre[s][2] = ap[2]; aPre[s][3] = ap[3];
        }

#pragma unroll
        for (int M = 0; M < 16; ++M) {
            short8 af = __builtin_bit_cast(short8, aPre[M & 1]);
            if (M <= 14) {                       // prefetch A(M+2), static slot
                const unsigned int* ap = abase + 128 * (M + 2);
                aPre[M & 1][0] = ap[0]; aPre[M & 1][1] = ap[1];
                aPre[M & 1][2] = ap[2]; aPre[M & 1][3] = ap[3];
            }
            short8 bPre = *(const short8*)(ybase + YADDR(yoff + 256 * (M + 8)));
            __builtin_amdgcn_s_setprio(1);
#pragma unroll
            for (int h = 0; h < 8; ++h)
                acc[h] = __builtin_amdgcn_mfma_f32_16x16x32_bf16(
                    af, cache[(h + M) & 7], acc[h], 0, 0, 0);
            __builtin_amdgcn_s_setprio(0);
            cache[M & 7] = bPre;
        }

        if (p == 0) {                            // extra M=16 (A(16) in slot 0)
            short8 af = __builtin_bit_cast(short8, aPre[0]);
            __builtin_amdgcn_s_setprio(1);
#pragma unroll
            for (int h = 0; h < 8; ++h)
                acc[h] = __builtin_amdgcn_mfma_f32_16x16x32_bf16(
                    af, cache[h], acc[h], 0, 0, 0);
            __builtin_amdgcn_s_setprio(0);
        }
    }

    // ---- cross-wave reduction (LDS as 2 x 2048 f32, swizzled f32x4) ----
    __syncthreads();
    float* red = (float*)lds;
    const int jb = RSWZ(16 * nn + 4 * q);        // swizzled quad base in h-block

    if (wv >= 2) {
        float* dst = red + (wv - 2) * 2048;
#pragma unroll
        for (int h = 0; h < 8; ++h)
            *(f32x4*)(dst + 256 * h + jb) = acc[h];
    }
    __syncthreads();
    if (wv < 2) {
        const float* src = red + wv * 2048;
#pragma unroll
        for (int h = 0; h < 8; ++h) {
            f32x4 v = *(const f32x4*)(src + 256 * h + jb);
            acc[h] += v;
        }
    }
    __syncthreads();
    if (wv < 2) {
        float* dst = red + wv * 2048;
#pragma unroll
        for (int h = 0; h < 8; ++h)
            *(f32x4*)(dst + 256 * h + jb) = acc[h];
    }
    __syncthreads();

    // ---- final sum + store to own slab out-third (block-private) ----
    float* slabf = (float*)(slab + O_OFF) + 2048 * half;
#pragma unroll
    for (int j = 0; j < 2; ++j) {
        int t = 4 * tid + 1024 * j;              // t_local, 4-aligned
        int ph = (t & ~255) + RSWZ(t & 255);     // physical (swizzled) index
        f32x4 v0 = *(const f32x4*)(red + ph);
        f32x4 v1 = *(const f32x4*)(red + 2048 + ph);
        *(f32x4*)(slabf + t) = v0 + v1;
    }
}

// ---------------------------------------------------------------------------
// K2: slab(b,f) out[t] f32 -> out[b][t][f]; f32x4 global reads AND writes.
__global__ __launch_bounds__(256)
void k2_out(const unsigned short* __restrict__ ws, float* __restrict__ out) {
    __shared__ float tile[32][33];
    const int blk = blockIdx.x;
    const int b  = blk & 31;                     // bid%8 == b%8 (XCD-local)
    const int t0 = (blk >> 5) << 5;
    const int tid = threadIdx.x;

    {
        int f = tid >> 3, k = tid & 7;
        f32x4 v = *(const f32x4*)(
            (const float*)(ws + (size_t)(b * 32 + f) * SLAB_US + O_OFF) + t0 + 4 * k);
        tile[f][4 * k + 0] = v[0];
        tile[f][4 * k + 1] = v[1];
        tile[f][4 * k + 2] = v[2];
        tile[f][4 * k + 3] = v[3];
    }
    __syncthreads();
    {
        int tl = tid >> 3, g = tid & 7;
        f32x4 v;
        v[0] = tile[4 * g + 0][tl];
        v[1] = tile[4 * g + 1][tl];
        v[2] = tile[4 * g + 2][tl];
        v[3] = tile[4 * g + 3][tl];
        *(f32x4*)(out + (size_t)b * (T_LEN * F_CH) + (t0 + tl) * F_CH + 4 * g) = v;
    }
}

// ---------------------------------------------------------------------------
extern "C" void kernel_launch(void* const* d_in, const int* in_sizes, int n_in,
                              void* d_out, int out_size, void* d_ws, size_t ws_size,
                              hipStream_t stream) {
    const float* X = (const float*)d_in[0];
    float* out = (float*)d_out;
    (void)in_sizes; (void)n_in; (void)out_size; (void)ws_size;
    unsigned short* ws = (unsigned short*)d_ws;

    k0_stage<<<dim3(1024), dim3(256), 0, stream>>>(X, ws);
    corr1d_mfma_kernel<<<dim3(2048), dim3(256), 0, stream>>>(ws);
    k2_out<<<dim3(4096), dim3(256), 0, stream>>>(ws, out);
}

// Round 13
// 44.133 us; speedup vs baseline: 1.0615x; 1.0615x over previous
//
#include <hip/hip_runtime.h>

// ---------------------------------------------------------------------------
// Depthwise 1-D full correlation, per (batch, filter):
//   out[t] = sum_s y[s] * w[2047 + s - t],   t, s in [0, 4096)
// K0: transpose/convert X[b][s][c] (f32) -> bf16 slabs ws[(b,f)] = [y|w]
// K1: block-Toeplitz bf16 MFMA (16x16x32), fp32 accumulate; one block per
//     (b,f); WB (+1-shifted w) built during staging from registers; 2-deep
//     static-indexed A prefetch; swizzled f32x4 reduction; result f32
//     overwrites own slab (block-private).
// K2: 32x32 transpose slabs -> out[b][t][f]; f32x4 on both global sides;
//     one writer per 128-B output line.
// All three kernels decode b = bid&31 so bid%8 == b%8: slab pipeline stays
// XCD-local in L2.
// ---------------------------------------------------------------------------

#define T_LEN 4096
#define F_CH  32
#define SLAB_US 8192              // y[4096] | w[4096]  (bf16)

// K1 LDS layout (ushort units)
#define WAo    8448               // WA[16+i] = w[i]
#define WBo    12592              // WB[15+i] = w[i]  (built during staging)
#define LDS_US 17120              // 34240 B (pad covers tail prefetch reads)

using short8 = __attribute__((ext_vector_type(8))) short;
using f32x4  = __attribute__((ext_vector_type(4))) float;
using uint4v = __attribute__((ext_vector_type(4))) unsigned int;

__device__ __forceinline__ unsigned short bf16b(float x) {
    unsigned int u = __float_as_uint(x);
    u += 0x7FFFu + ((u >> 16) & 1u);      // RNE
    return (unsigned short)(u >> 16);
}

// y-region swizzle: granule g -> g ^ ((g>>3)&7)  (bijective per 8-block)
#define YADDR(e) ((((e) >> 3) ^ (((e) >> 6) & 7)) << 3)
// reduction swizzle within a 256-dword h-block: j ^ ((nn&7)<<2), nn = j>>4
#define RSWZ(j)  ((j) ^ ((((j) >> 4) & 7) << 2))

// ---------------------------------------------------------------------------
__global__ __launch_bounds__(256)
void k0_stage(const float* __restrict__ X, unsigned short* __restrict__ ws) {
    __shared__ unsigned short tile[64 * 130];
    const int tid = threadIdx.x;
    const int b  = blockIdx.x & 31;              // bid%8 == b%8 (XCD-local)
    const int s0 = (blockIdx.x >> 5) << 7;       // 128-row tile

    const float* xb = X + ((size_t)b * T_LEN + s0) * 64;
#pragma unroll
    for (int i = 0; i < 8; ++i) {
        int d4 = 4 * (tid + 256 * i);            // dword idx, 4 per thread
        int row = d4 >> 6, c0 = d4 & 63;
        f32x4 xv = *(const f32x4*)(xb + (size_t)row * 64 + c0);
#pragma unroll
        for (int k = 0; k < 4; ++k)
            tile[(c0 + k) * 130 + row] = bf16b(xv[k]);
    }
    __syncthreads();

    // y & w slabs, dword stores (coalesced per wave)
#pragma unroll
    for (int i = 0; i < 16; ++i) {
        int dw = tid + 256 * i;                  // 0..4095
        int c = dw >> 6, j0 = (dw & 63) * 2;
        unsigned int two = (unsigned int)tile[c * 130 + j0]
                         | ((unsigned int)tile[c * 130 + j0 + 1] << 16);
        unsigned short* slab;
        int off;
        if (c < 32) { slab = ws + (size_t)(b * 32 + c) * SLAB_US; off = s0 + j0; }
        else { slab = ws + (size_t)(b * 32 + (c - 32)) * SLAB_US; off = 4096 + s0 + j0; }
        *(unsigned int*)(slab + off) = two;
    }
}

// ---------------------------------------------------------------------------
__global__ __launch_bounds__(256, 3)
void corr1d_mfma_kernel(unsigned short* __restrict__ ws) {
    __shared__ __align__(16) unsigned short lds[LDS_US];
    const int tid = threadIdx.x;
    const int b = blockIdx.x & 31;               // bid%8 == b%8 (XCD-local)
    const int f = blockIdx.x >> 5;
    unsigned short* slab = ws + (size_t)(b * 32 + f) * SLAB_US;

    // ---- zero pad regions ----
    f32x4 z4 = (f32x4)0.0f;
    *(f32x4*)(lds + 8 * tid) = z4;                            // y gran [0,256)
    *(f32x4*)(lds + 8 * (768 + tid)) = z4;                    // y gran [768,1024)
    if (tid < 32) *(f32x4*)(lds + 8 * (1024 + tid)) = z4;     // y gran [1024,1056)
    if (tid < 2)       *(f32x4*)(lds + WAo + 8 * tid) = z4;              // WA [0,16)
    else if (tid < 6)  *(f32x4*)(lds + WAo + 4112 + 8 * (tid - 2)) = z4; // WA [4112,4144)
    else if (tid == 6) {
        *(f32x4*)(lds + WBo) = z4;                                       // WB [0,8)
        for (int i = 8; i < 14; ++i) lds[WBo + i] = 0;        // WB[8..14)
    } else if (tid >= 8 && tid < 12)
        *(f32x4*)(lds + WBo + 4112 + 8 * (tid - 8)) = z4;                // WB [4112,4144)

    // ---- stage y, WA, WB (coalesced uint4; WB shifted in registers) ----
    const uint4v* sv = (const uint4v*)slab;
    unsigned int* wb32 = (unsigned int*)(lds + WBo);
#pragma unroll
    for (int r = 0; r < 2; ++r) {
        int c = tid + 256 * r;                   // 0..511
        uint4v vy = sv[c];
        int g = 256 + c;
        *(uint4v*)(lds + ((g ^ ((g >> 3) & 7)) << 3)) = vy;   // swizzled y
        uint4v vw = sv[512 + c];                 // w[8c .. 8c+7]
        *(uint4v*)(lds + WAo + 16 + 8 * c) = vw;
        // WB[15+i] = w[i]: 4 shifted dwords at wb32[7+4c+k]
        unsigned int wm1 = (c == 0) ? 0u
                         : (unsigned int)slab[4096 + 8 * c - 1];
        unsigned int v0 = vw[0], v1 = vw[1], v2 = vw[2], v3 = vw[3];
        wb32[7 + 4 * c + 0] = (wm1 & 0xFFFFu) | (v0 << 16);
        wb32[7 + 4 * c + 1] = (v0 >> 16) | (v1 << 16);
        wb32[7 + 4 * c + 2] = (v1 >> 16) | (v2 << 16);
        wb32[7 + 4 * c + 3] = (v2 >> 16) | (v3 << 16);
        if (c == 511) wb32[2055] = (v3 >> 16);   // (w[4095], 0)
    }
    __syncthreads();

    // ---- compute (verified core; 2-deep static A prefetch) ----
    const int lane = tid & 63;
    const int wv   = tid >> 6;
    const int nn   = lane & 15;
    const int q    = lane >> 4;
    const int ko   = q << 3;

    f32x4 acc[16];
#pragma unroll
    for (int h = 0; h < 16; ++h) acc[h] = (f32x4)0.0f;

    short8 cache[16];

    const int tiOdd = nn & 1;
    const unsigned short* wbase = tiOdd ? &lds[WAo] : &lds[WBo];
    const int aoff0 = (tiOdd ? 15 : 14) + ko - nn;           // even, >= 0
    const unsigned short* ybase = &lds[0];
    const int yoff0 = 16 * nn + ko;

    for (int pp = 0; pp < 2; ++pp) {
        const int p = wv * 2 + pp;                           // pass 0..7
        const int yoff = yoff0 + 32 * p;
        const unsigned int* abase =
            (const unsigned int*)(wbase + (aoff0 + 32 * p));

#pragma unroll
        for (int s = 0; s < 16; ++s)
            cache[s] = *(const short8*)(ybase + YADDR(yoff + 256 * s));

        uint4v aPre[2];
#pragma unroll
        for (int s = 0; s < 2; ++s) {
            const unsigned int* ap = abase + 128 * s;
            aPre[s][0] = ap[0]; aPre[s][1] = ap[1];
            aPre[s][2] = ap[2]; aPre[s][3] = ap[3];
        }

#pragma unroll
        for (int M = 0; M < 16; ++M) {
            short8 af = __builtin_bit_cast(short8, aPre[M & 1]);
            if (M <= 14) {                       // prefetch A(M+2), static slot
                const unsigned int* ap = abase + 128 * (M + 2);
                aPre[M & 1][0] = ap[0]; aPre[M & 1][1] = ap[1];
                aPre[M & 1][2] = ap[2]; aPre[M & 1][3] = ap[3];
            }
            short8 bPre = *(const short8*)(ybase + YADDR(yoff + 256 * (M + 16)));
            __builtin_amdgcn_s_setprio(1);
#pragma unroll
            for (int h = 0; h < 16; ++h)
                acc[h] = __builtin_amdgcn_mfma_f32_16x16x32_bf16(
                    af, cache[(h + M) & 15], acc[h], 0, 0, 0);
            __builtin_amdgcn_s_setprio(0);
            cache[M] = bPre;
        }

        if (p == 0) {                            // extra M=16 (A(16) in slot 0)
            short8 af = __builtin_bit_cast(short8, aPre[0]);
            __builtin_amdgcn_s_setprio(1);
#pragma unroll
            for (int h = 0; h < 16; ++h)
                acc[h] = __builtin_amdgcn_mfma_f32_16x16x32_bf16(
                    af, cache[h], acc[h], 0, 0, 0);
            __builtin_amdgcn_s_setprio(0);
        }
    }

    // ---- cross-wave reduction (LDS as 2 x 4096 f32, swizzled f32x4) ----
    __syncthreads();
    float* red = (float*)lds;
    const int jb = RSWZ(16 * nn + 4 * q);        // swizzled quad base in h-block

    if (wv >= 2) {
        float* dst = red + (wv - 2) * 4096;
#pragma unroll
        for (int h = 0; h < 16; ++h)
            *(f32x4*)(dst + 256 * h + jb) = acc[h];
    }
    __syncthreads();
    if (wv < 2) {
        const float* src = red + wv * 4096;
#pragma unroll
        for (int h = 0; h < 16; ++h) {
            f32x4 v = *(const f32x4*)(src + 256 * h + jb);
            acc[h] += v;
        }
    }
    __syncthreads();
    if (wv < 2) {
        float* dst = red + wv * 4096;
#pragma unroll
        for (int h = 0; h < 16; ++h)
            *(f32x4*)(dst + 256 * h + jb) = acc[h];
    }
    __syncthreads();

    // ---- final sum + store to own slab (block-private) ----
    float* slabf = (float*)slab;
#pragma unroll
    for (int j = 0; j < 4; ++j) {
        int t = 4 * tid + 1024 * j;              // logical t, 4-aligned
        int ph = (t & ~255) + RSWZ(t & 255);     // physical (swizzled) index
        f32x4 v0 = *(const f32x4*)(red + ph);
        f32x4 v1 = *(const f32x4*)(red + 4096 + ph);
        *(f32x4*)(slabf + t) = v0 + v1;
    }
}

// ---------------------------------------------------------------------------
// K2: slab(b,f)[t] f32 -> out[b][t][f]; f32x4 global reads AND writes.
__global__ __launch_bounds__(256)
void k2_out(const unsigned short* __restrict__ ws, float* __restrict__ out) {
    __shared__ float tile[32][33];
    const int blk = blockIdx.x;
    const int b  = blk & 31;                     // bid%8 == b%8 (XCD-local)
    const int t0 = (blk >> 5) << 5;
    const int tid = threadIdx.x;

    // load: thread (f = tid>>3, k = tid&7) reads slab_f[t0+4k .. +3]
    {
        int f = tid >> 3, k = tid & 7;
        f32x4 v = *(const f32x4*)(
            (const float*)(ws + (size_t)(b * 32 + f) * SLAB_US) + t0 + 4 * k);
        tile[f][4 * k + 0] = v[0];
        tile[f][4 * k + 1] = v[1];
        tile[f][4 * k + 2] = v[2];
        tile[f][4 * k + 3] = v[3];
    }
    __syncthreads();
    // store: thread (tl = tid>>3, g = tid&7) writes out[b][t0+tl][4g .. +3]
    {
        int tl = tid >> 3, g = tid & 7;
        f32x4 v;
        v[0] = tile[4 * g + 0][tl];
        v[1] = tile[4 * g + 1][tl];
        v[2] = tile[4 * g + 2][tl];
        v[3] = tile[4 * g + 3][tl];
        *(f32x4*)(out + (size_t)b * (T_LEN * F_CH) + (t0 + tl) * F_CH + 4 * g) = v;
    }
}

// ---------------------------------------------------------------------------
extern "C" void kernel_launch(void* const* d_in, const int* in_sizes, int n_in,
                              void* d_out, int out_size, void* d_ws, size_t ws_size,
                              hipStream_t stream) {
    const float* X = (const float*)d_in[0];
    float* out = (float*)d_out;
    (void)in_sizes; (void)n_in; (void)out_size; (void)ws_size;
    unsigned short* ws = (unsigned short*)d_ws;

    k0_stage<<<dim3(1024), dim3(256), 0, stream>>>(X, ws);
    corr1d_mfma_kernel<<<dim3(1024), dim3(256), 0, stream>>>(ws);
    k2_out<<<dim3(4096), dim3(256), 0, stream>>>(ws, out);
}